// Round 1
// baseline (111.700 us; speedup 1.0000x reference)
//
#include <hip/hip_runtime.h>
#include <stdint.h>

#define D_K 512
#define B_ROWS 512
#define C_CLS 85742
#define N_TILES 670            // ceil(85742/128)
#define N_PART (N_TILES * 2)   // one partial per (ntile, wave-col-half)

using bf16x8 = __attribute__((ext_vector_type(8))) short;
using f32x4  = __attribute__((ext_vector_type(4))) float;

__device__ __forceinline__ unsigned short f2bf(float f) {
  unsigned int u = __builtin_bit_cast(unsigned int, f);
  u += 0x7FFFu + ((u >> 16) & 1u);          // round-to-nearest-even
  return (unsigned short)(u >> 16);
}
__device__ __forceinline__ float bf2f(unsigned short h) {
  return __builtin_bit_cast(float, ((unsigned int)h) << 16);
}
__device__ __forceinline__ float sq8(const float4& a, const float4& b) {
  return a.x*a.x + a.y*a.y + a.z*a.z + a.w*a.w +
         b.x*b.x + b.y*b.y + b.z*b.z + b.w*b.w;
}
__device__ __forceinline__ void pack8(const float4& a, const float4& b, unsigned short* h) {
  h[0]=f2bf(a.x); h[1]=f2bf(a.y); h[2]=f2bf(a.z); h[3]=f2bf(a.w);
  h[4]=f2bf(b.x); h[5]=f2bf(b.y); h[6]=f2bf(b.z); h[7]=f2bf(b.w);
}

// ---------------- Pass A: normalize x -> bf16 xn, save ||x|| ----------------
__global__ __launch_bounds__(256) void k_xnorm(const float* __restrict__ X,
                                               unsigned short* __restrict__ XN,
                                               float* __restrict__ FN) {
  int row  = blockIdx.x * 4 + (threadIdx.x >> 6);
  int lane = threadIdx.x & 63;
  const float4* px = (const float4*)(X + (size_t)row * D_K + lane * 8);
  float4 u = px[0], v = px[1];
  float nsq = sq8(u, v);
#pragma unroll
  for (int m = 1; m <= 32; m <<= 1) nsq += __shfl_xor(nsq, m);
  float nrm = sqrtf(nsq);
  float inv = 1.0f / fmaxf(nrm, 1e-12f);
  float4 a = make_float4(u.x*inv, u.y*inv, u.z*inv, u.w*inv);
  float4 b = make_float4(v.x*inv, v.y*inv, v.z*inv, v.w*inv);
  alignas(16) unsigned short h[8];
  pack8(a, b, h);
  *(bf16x8*)(XN + (size_t)row * D_K + lane * 8) = *(const bf16x8*)h;
  if (lane == 0) FN[row] = nrm;
}

// ---- Pass C: 128x128 bf16 MFMA GEMM (A = xn bf16 via global_load_lds,
// ----  B = raw W fp32 reg-staged -> bf16 LDS, with in-loop ||w||^2), epilogue
// ----  computes per-(row, 64-col) (max, sumexp) partials of z = clamp(cos)*||x||.
__global__ __launch_bounds__(256) void k_gemm_lse(const float* __restrict__ W,
                                                  const unsigned short* __restrict__ XN,
                                                  const float* __restrict__ FN,
                                                  float2* __restrict__ PART) {
  __shared__ alignas(16) unsigned short As[128 * 32];
  __shared__ alignas(16) unsigned short Bs[128 * 32];
  __shared__ float nsqS[128];
  __shared__ float fnS[128];

  int bid = blockIdx.x;
  // bijective XCD chunking: nwg=2680, 2680/8=335 -> each XCD gets contiguous
  // n-tiles, and all 4 m-blocks of an n-tile stay on one XCD (B-tile L2 reuse).
  int wg    = (bid & 7) * 335 + (bid >> 3);
  int ntile = wg >> 2, mtile = wg & 3;
  int m0 = mtile * 128, n0 = ntile * 128;

  int t    = threadIdx.x;
  int lane = t & 63, wid = t >> 6;
  int wm = wid >> 1, wn = wid & 1;
  int s = lane & 15, g = lane >> 4;

  // B staging: thread t owns rows r1=t>>2 and r2=64+(t>>2), cols (t&3)*8..+7
  int r1 = t >> 2;
  int c0 = (t & 3) * 8;
  int gr1 = n0 + r1, gr2 = n0 + 64 + r1;
  bool v1 = gr1 < C_CLS, v2 = gr2 < C_CLS;
  const float* pB1 = W + (size_t)gr1 * D_K + c0;
  const float* pB2 = W + (size_t)gr2 * D_K + c0;

  // A staging via global_load_lds(16B): lds dest = wave-uniform base + lane*16
  int lin0 = wid * 512 + lane * 8;        // element offset in As, inst 0
  int lin1 = 2048 + lin0;                 // inst 1
  const unsigned short* gA0 = XN + (size_t)(m0 + (lin0 >> 5)) * D_K + (lin0 & 31);
  const unsigned short* gA1 = XN + (size_t)(m0 + (lin1 >> 5)) * D_K + (lin1 & 31);
  unsigned short* ldsA0 = As + wid * 512;
  unsigned short* ldsA1 = As + 2048 + wid * 512;

  f32x4 acc[4][4] = {};
  float nsq1 = 0.f, nsq2 = 0.f;

  float4 ra0, ra1, rb0, rb1;
  float4 z4 = make_float4(0.f, 0.f, 0.f, 0.f);
  if (v1) { ra0 = *(const float4*)pB1; ra1 = *(const float4*)(pB1 + 4); } else { ra0 = z4; ra1 = z4; }
  if (v2) { rb0 = *(const float4*)pB2; rb1 = *(const float4*)(pB2 + 4); } else { rb0 = z4; rb1 = z4; }

  for (int kt = 0; kt < 16; ++kt) {
    __syncthreads();                       // prev iter's LDS reads done
    nsq1 += sq8(ra0, ra1);                 // ||w||^2 from fp32 (pre-cast) values
    nsq2 += sq8(rb0, rb1);
    alignas(16) unsigned short h1[8], h2[8];
    pack8(ra0, ra1, h1);
    pack8(rb0, rb1, h2);
    *(bf16x8*)(Bs + t * 8)        = *(const bf16x8*)h1;   // bytes t*16 (packed)
    *(bf16x8*)(Bs + 2048 + t * 8) = *(const bf16x8*)h2;
    __builtin_amdgcn_global_load_lds(
        (const __attribute__((address_space(1))) unsigned int*)(gA0 + kt * 32),
        (__attribute__((address_space(3))) unsigned int*)ldsA0, 16, 0, 0);
    __builtin_amdgcn_global_load_lds(
        (const __attribute__((address_space(1))) unsigned int*)(gA1 + kt * 32),
        (__attribute__((address_space(3))) unsigned int*)ldsA1, 16, 0, 0);
    __syncthreads();                       // LDS visible (barrier drains vm/lgkm)
    if (kt + 1 < 16) {                     // prefetch next B under the MFMA phase
      const float* q1 = pB1 + (kt + 1) * 32;
      const float* q2 = pB2 + (kt + 1) * 32;
      if (v1) { ra0 = *(const float4*)q1; ra1 = *(const float4*)(q1 + 4); }
      if (v2) { rb0 = *(const float4*)q2; rb1 = *(const float4*)(q2 + 4); }
    }
    bf16x8 af[4], bfr[4];
#pragma unroll
    for (int mf = 0; mf < 4; ++mf)
      af[mf] = *(const bf16x8*)(As + (wm * 64 + mf * 16 + s) * 32 + g * 8);
#pragma unroll
    for (int nf = 0; nf < 4; ++nf)
      bfr[nf] = *(const bf16x8*)(Bs + (wn * 64 + nf * 16 + s) * 32 + g * 8);
#pragma unroll
    for (int mf = 0; mf < 4; ++mf)
#pragma unroll
      for (int nf = 0; nf < 4; ++nf)
        acc[mf][nf] = __builtin_amdgcn_mfma_f32_16x16x32_bf16(af[mf], bfr[nf], acc[mf][nf], 0, 0, 0);
  }

  // finish per-row ||w||^2: combine the 4 col-chunk owners (lanes t, t^1, t^2)
  nsq1 += __shfl_xor(nsq1, 1); nsq1 += __shfl_xor(nsq1, 2);
  nsq2 += __shfl_xor(nsq2, 1); nsq2 += __shfl_xor(nsq2, 2);
  if ((t & 3) == 0) { nsqS[r1] = nsq1; nsqS[64 + r1] = nsq2; }
  if (t < 128) fnS[t] = FN[m0 + t];
  __syncthreads();

  float rinv[4]; int cvalid[4];
#pragma unroll
  for (int nf = 0; nf < 4; ++nf) {
    int cl = wn * 64 + nf * 16 + s;
    cvalid[nf] = (n0 + cl) < C_CLS;
    rinv[nf] = 1.0f / fmaxf(sqrtf(nsqS[cl]), 1e-12f);
  }
  const float NEG_INF = -__builtin_inff();
#pragma unroll
  for (int mf = 0; mf < 4; ++mf) {
#pragma unroll
    for (int q = 0; q < 4; ++q) {
      int rl = wm * 64 + mf * 16 + g * 4 + q;     // D row = (lane>>4)*4+reg
      float fr = fnS[rl];
      float z[4]; float mx = NEG_INF;
#pragma unroll
      for (int nf = 0; nf < 4; ++nf) {
        float cc = acc[mf][nf][q] * rinv[nf];
        cc = fminf(fmaxf(cc, -1.0f), 1.0f);
        z[nf] = cvalid[nf] ? cc * fr : NEG_INF;
        mx = fmaxf(mx, z[nf]);
      }
#pragma unroll
      for (int d = 1; d <= 8; d <<= 1) mx = fmaxf(mx, __shfl_xor(mx, d));
      float se = 0.f;
#pragma unroll
      for (int nf = 0; nf < 4; ++nf) se += __expf(z[nf] - mx);  // exp(-inf)=0
#pragma unroll
      for (int d = 1; d <= 8; d <<= 1) se += __shfl_xor(se, d);
      if (s == mf * 4 + q)
        PART[(size_t)(m0 + rl) * N_PART + (ntile * 2 + wn)] = make_float2(mx, se);
    }
  }
}

// ------- Pass D: per-row target logit (unmodified + margin-modified) --------
__global__ __launch_bounds__(64) void k_target(const float* __restrict__ W,
                                               const unsigned short* __restrict__ XN,
                                               const float* __restrict__ FN,
                                               const int* __restrict__ LBL,
                                               float2* __restrict__ ZT) {
  int row = blockIdx.x;
  int lane = threadIdx.x;
  int lab = LBL[row];
  const float* pw = W + (size_t)lab * D_K + lane * 8;
  const unsigned short* px = XN + (size_t)row * D_K + lane * 8;
  float dot = 0.f, nsq = 0.f;
#pragma unroll
  for (int j = 0; j < 8; ++j) {
    float w = pw[j];
    nsq += w * w;
    dot += bf2f(px[j]) * bf2f(f2bf(w));   // match GEMM numerics (bf16 operands)
  }
#pragma unroll
  for (int m = 1; m <= 32; m <<= 1) { dot += __shfl_xor(dot, m); nsq += __shfl_xor(nsq, m); }
  if (lane == 0) {
    const float LAMB = 1000.0f / 1.12f;   // iter=1 -> max(5, 1000/1.12)
    float rinv = 1.0f / fmaxf(sqrtf(nsq), 1e-12f);
    float c = fminf(fmaxf(dot * rinv, -1.0f), 1.0f);
    float c2 = c * c;
    float cm = 8.0f * c2 * c2 - 8.0f * c2 + 1.0f;   // cos(4θ)
    float th = acosf(c);
    float kf = floorf(4.0f * th / 3.14159265f);
    float phi = ((((int)kf) & 1) ? -cm : cm) - 2.0f * kf;
    float fr = FN[row];
    float zu = fr * c;
    float zm = fr * (c + (phi - c) / (1.0f + LAMB));
    ZT[row] = make_float2(zu, zm);
  }
}

// ------- Pass E1: combine 1340 partials per row -> per-row CE loss ----------
__global__ __launch_bounds__(256) void k_lse(const float2* __restrict__ PART,
                                             const float2* __restrict__ ZT,
                                             float* __restrict__ LOSSI) {
  int row = blockIdx.x;
  int t = threadIdx.x;
  const float NEG_INF = -__builtin_inff();
  float m = NEG_INF, ss = 0.f;
  for (int p = t; p < N_PART; p += 256) {
    float2 ps = PART[(size_t)row * N_PART + p];
    if (ps.y > 0.f) {
      if (ps.x > m) { ss = ss * __expf(m - ps.x) + ps.y; m = ps.x; }
      else          { ss += ps.y * __expf(ps.x - m); }
    }
  }
  __shared__ float sm[256], sv[256];
  sm[t] = m; sv[t] = ss;
  __syncthreads();
  for (int o = 128; o > 0; o >>= 1) {
    if (t < o) {
      float m1 = sm[t], s1 = sv[t];
      float m2 = sm[t + o], s2 = sv[t + o];
      float mm = fmaxf(m1, m2);
      float e1 = (m1 > NEG_INF) ? s1 * __expf(m1 - mm) : 0.f;
      float e2 = (m2 > NEG_INF) ? s2 * __expf(m2 - mm) : 0.f;
      sm[t] = mm; sv[t] = e1 + e2;
    }
    __syncthreads();
  }
  if (t == 0) {
    float M = sm[0], S = sv[0];
    float2 zt = ZT[row];
    // swap the target's unmodified exp term for the margin-modified one
    S += __expf(zt.y - M) - __expf(zt.x - M);
    LOSSI[row] = M + logf(S) - zt.y;
  }
}

// ------- Pass E2: mean over 512 rows -> scalar loss -------------------------
__global__ __launch_bounds__(256) void k_mean(const float* __restrict__ LOSSI,
                                              float* __restrict__ OUT) {
  int t = threadIdx.x;
  float s_ = LOSSI[t] + LOSSI[t + 256];
#pragma unroll
  for (int m = 1; m <= 32; m <<= 1) s_ += __shfl_xor(s_, m);
  __shared__ float wsum[4];
  if ((t & 63) == 0) wsum[t >> 6] = s_;
  __syncthreads();
  if (t == 0) OUT[0] = (wsum[0] + wsum[1] + wsum[2] + wsum[3]) * (1.0f / 512.0f);
}

extern "C" void kernel_launch(void* const* d_in, const int* in_sizes, int n_in,
                              void* d_out, int out_size, void* d_ws, size_t ws_size,
                              hipStream_t stream) {
  const float* X   = (const float*)d_in[0];   // [512,512] f32
  const float* W   = (const float*)d_in[1];   // [85742,512] f32
  const int*   LBL = (const int*)d_in[2];     // [512] i32
  float* OUT = (float*)d_out;

  char* ws = (char*)d_ws;
  unsigned short* XN = (unsigned short*)ws;            // 512*512*2       = 524288
  float*  FN    = (float*)(ws + 524288);               // 512*4           = 2048
  float2* ZT    = (float2*)(ws + 526336);              // 512*8           = 4096
  float*  LOSSI = (float*)(ws + 530432);               // 512*4           = 2048
  float2* PART  = (float2*)(ws + 532480);              // 512*1340*8      = 5488640

  k_xnorm  <<<dim3(128),  dim3(256), 0, stream>>>(X, XN, FN);
  k_gemm_lse<<<dim3(2680), dim3(256), 0, stream>>>(W, XN, FN, PART);
  k_target <<<dim3(512),  dim3(64),  0, stream>>>(W, XN, FN, LBL, ZT);
  k_lse    <<<dim3(512),  dim3(256), 0, stream>>>(PART, ZT, LOSSI);
  k_mean   <<<dim3(1),    dim3(256), 0, stream>>>(LOSSI, OUT);
}